// Round 14
// baseline (266.303 us; speedup 1.0000x reference)
//
#include <hip/hip_runtime.h>
#include <hip/hip_bf16.h>

// ---------------------------------------------------------------------------
// DeformableTransformerDecoderLayer on MI355X — round 14:
//  - gemm_vdir (value proj): W resident in LDS (one barrier), then barrier-free
//    K-loop with per-lane A->reg loads over the IDENTITY row map (16 rows x
//    128B dense per wave instr). K=256 is too short for the 2-barrier loop
//    (4 steps = all prologue); zero barriers lets the compiler pipeline.
//  - QKV fused into one N=768 GEMM (A source: tgt+pos for n<512, tgt after).
// ---------------------------------------------------------------------------

namespace {
constexpr int D_ = 256;
constexpr int NQ_ = 900;
constexpr int BS_ = 8;
constexpr int NH_ = 8;
constexpr int HD_ = 32;
constexpr int DFF_ = 1024;
constexpr int MTOK = NQ_ * BS_;       // 7200
constexpr int LMEM_ = 13294;
constexpr long T = (long)MTOK * D_;   // 1843200
constexpr float QSC = 0.17677669529663687f;  // 1/sqrt(32)
constexpr int QKVS = 768;             // fused QKV row stride
constexpr int MVAL = BS_ * LMEM_;     // 106352
}

typedef __attribute__((ext_vector_type(8))) short bf8_t;
typedef __attribute__((ext_vector_type(4))) float f4_t;

#define MFMA16(a, b, c) __builtin_amdgcn_mfma_f32_16x16x32_bf16((a), (b), (c), 0, 0, 0)

__device__ __forceinline__ unsigned short bfbits(float x) {
    union { __hip_bfloat16 h; unsigned short u; } cv;
    cv.h = __float2bfloat16(x);
    return cv.u;
}
__device__ __forceinline__ float bf2f(unsigned short u) {
    union { float f; unsigned v; } cv;
    cv.v = ((unsigned)u) << 16;
    return cv.f;
}

__device__ __forceinline__ void gload16(const unsigned short* g, unsigned short* l) {
    __builtin_amdgcn_global_load_lds(
        (const __attribute__((address_space(1))) unsigned int*)(g),
        (__attribute__((address_space(3))) unsigned int*)(l), 16, 0, 0);
}
__device__ __forceinline__ void gload16f(const float* g, float* l) {
    __builtin_amdgcn_global_load_lds(
        (const __attribute__((address_space(1))) unsigned int*)(g),
        (__attribute__((address_space(3))) unsigned int*)(l), 16, 0, 0);
}

// fused weight conversion; Wq scaled by QSC; biasAll = [qkv bias 768 | oa bias 384]
__global__ void conv_weights(
    const float* __restrict__ ipw, const float* __restrict__ opw,
    const float* __restrict__ sow, const float* __restrict__ aww,
    const float* __restrict__ vpw, const float* __restrict__ outpw,
    const float* __restrict__ l1w, const float* __restrict__ l2w,
    const float* __restrict__ ipb, const float* __restrict__ sob,
    const float* __restrict__ awb,
    unsigned short* __restrict__ Wbf, float* __restrict__ biasAll)
{
    if (blockIdx.x == 0) {
        for (int j = threadIdx.x; j < 768; j += 256)
            biasAll[j] = (j < 256) ? ipb[j] * QSC : ipb[j];
        for (int j = threadIdx.x; j < 384; j += 256)
            biasAll[768 + j] = (j < 256) ? sob[j] : awb[j - 256];
    }
    const long idx4 = (long)blockIdx.x * 256 + threadIdx.x;
    if (idx4 >= 253952) return;
    const long e = idx4 * 4;
    const float* src; long off; float sc = 1.f;
    if (e < 196608)      { src = ipw;   off = 0;      if (e < 65536) sc = QSC; }
    else if (e < 262144) { src = opw;   off = 196608; }
    else if (e < 327680) { src = sow;   off = 262144; }
    else if (e < 360448) { src = aww;   off = 327680; }
    else if (e < 425984) { src = vpw;   off = 360448; }
    else if (e < 491520) { src = outpw; off = 425984; }
    else if (e < 753664) { src = l1w;   off = 491520; }
    else                 { src = l2w;   off = 753664; }
    const float4 v = *(const float4*)(src + (e - off));
    union { unsigned short u[4]; uint2 w; } pk;
    pk.u[0] = bfbits(v.x * sc); pk.u[1] = bfbits(v.y * sc);
    pk.u[2] = bfbits(v.z * sc); pk.u[3] = bfbits(v.w * sc);
    *(uint2*)(Wbf + e) = pk.w;
}

// ---------------- bf16-A MFMA GEMM (m97 single-buffer, swizzled reads) --------
template<bool RELU, bool OUTBF16>
__global__ __launch_bounds__(256) void gemm_mfma(
    const unsigned short* __restrict__ A, const unsigned short* __restrict__ W,
    const float* __restrict__ bias, void* __restrict__ C, int M, int N, int K)
{
    __shared__ unsigned short As[128 * 32];
    __shared__ unsigned short Ws[128 * 32];
    const int t = threadIdx.x;
    const long m0 = (long)blockIdx.x * 128;
    const int n0 = blockIdx.y * 128;
    const int row0 = t >> 2;
    const int cgp = (t & 3) ^ ((t >> 2) & 3);
    long ar0 = m0 + row0;        if (ar0 > M - 1) ar0 = M - 1;
    long ar1 = m0 + 64 + row0;   if (ar1 > M - 1) ar1 = M - 1;
    const unsigned short* ga0 = A + ar0 * K + cgp * 8;
    const unsigned short* ga1 = A + ar1 * K + cgp * 8;
    const unsigned short* gw0 = W + (long)(n0 + row0) * K + cgp * 8;
    const unsigned short* gw1 = W + (long)(n0 + 64 + row0) * K + cgp * 8;
    const int lane = t & 63, wave = t >> 6;
    const int c = lane & 15, g = lane >> 4;
    const int wr = wave >> 1, wc = wave & 1;
    const int sws = (g * 8) ^ ((c & 3) * 8);
    f4_t acc[4][4];
#pragma unroll
    for (int i = 0; i < 4; ++i)
#pragma unroll
        for (int j = 0; j < 4; ++j)
            acc[i][j] = f4_t{0.f, 0.f, 0.f, 0.f};

    for (int kb = 0; kb < K; kb += 32) {
        gload16(ga0 + kb, As + t * 8);
        gload16(ga1 + kb, As + 2048 + t * 8);
        gload16(gw0 + kb, Ws + t * 8);
        gload16(gw1 + kb, Ws + 2048 + t * 8);
        __syncthreads();
        bf8_t af[4], bfr[4];
#pragma unroll
        for (int i = 0; i < 4; ++i) {
            af[i] = *(const bf8_t*)(As + (wr * 64 + i * 16 + c) * 32 + sws);
            bfr[i] = *(const bf8_t*)(Ws + (wc * 64 + i * 16 + c) * 32 + sws);
        }
#pragma unroll
        for (int i = 0; i < 4; ++i)
#pragma unroll
            for (int j = 0; j < 4; ++j)
                acc[i][j] = MFMA16(af[i], bfr[j], acc[i][j]);
        __syncthreads();
    }

#pragma unroll
    for (int i = 0; i < 4; ++i) {
        const long rbase = m0 + wr * 64 + i * 16 + 4 * g;
#pragma unroll
        for (int j = 0; j < 4; ++j) {
            const int col = n0 + wc * 64 + j * 16 + c;
            const float bv = bias[col];
#pragma unroll
            for (int r = 0; r < 4; ++r) {
                const long rr = rbase + r;
                if (rr < M) {
                    float v = acc[i][j][r] + bv;
                    if (RELU) v = fmaxf(v, 0.f);
                    if (OUTBF16) ((unsigned short*)C)[rr * N + col] = bfbits(v);
                    else         ((float*)C)[rr * N + col] = v;
                }
            }
        }
    }
}

// ---------------- value projection: W-resident, barrier-free K-loop -----------
// A = memory fp32 (identity rows, contiguous). C = val bf16 [MVAL][256].
// Persistent grid (256, 2): 2 blocks/CU, each ~6-7 tiles of 64 rows.
__global__ __launch_bounds__(256) void gemm_vdir(
    const float* __restrict__ A, const unsigned short* __restrict__ W,
    const float* __restrict__ bias, unsigned short* __restrict__ C)
{
    __shared__ unsigned short Wl[128 * 256];   // 64KB, swizzled
    const int t = threadIdx.x;
    const int n0 = blockIdx.y * 128;
    {   // stage W once: LDS[r*256 + s*8] = W[n0+r][(s^(r&31))*8..]
        const int rsub = t >> 5, slot = t & 31;
#pragma unroll
        for (int i = 0; i < 16; ++i) {
            const int r = i * 8 + rsub;
            const int cg = slot ^ (r & 31);
            gload16(W + (long)(n0 + r) * 256 + cg * 8, Wl + r * 256 + slot * 8);
        }
    }
    __syncthreads();
    const int lane = t & 63, wave = t >> 6;
    const int c = lane & 15, g = lane >> 4;
    const int wr = wave >> 1, wc = wave & 1;

    for (int mt = blockIdx.x; mt < 1662; mt += 256) {
        const long m0 = (long)mt * 64;
        int r0 = (int)m0 + wr * 32 + c;      if (r0 > MVAL - 1) r0 = MVAL - 1;
        int r1 = r0 + 16;                    if (r1 > MVAL - 1) r1 = MVAL - 1;
        const float* pA0 = A + (long)r0 * 256 + g * 8;
        const float* pA1 = A + (long)r1 * 256 + g * 8;
        f4_t acc[2][4];
#pragma unroll
        for (int i = 0; i < 2; ++i)
#pragma unroll
            for (int j = 0; j < 4; ++j)
                acc[i][j] = f4_t{0.f, 0.f, 0.f, 0.f};
#pragma unroll
        for (int kk = 0; kk < 8; ++kk) {
            const float4 l0 = *(const float4*)(pA0 + kk * 32);
            const float4 h0 = *(const float4*)(pA0 + kk * 32 + 4);
            const float4 l1 = *(const float4*)(pA1 + kk * 32);
            const float4 h1 = *(const float4*)(pA1 + kk * 32 + 4);
            union { bf8_t v; unsigned short u[8]; } p0, p1;
            p0.u[0] = bfbits(l0.x); p0.u[1] = bfbits(l0.y); p0.u[2] = bfbits(l0.z); p0.u[3] = bfbits(l0.w);
            p0.u[4] = bfbits(h0.x); p0.u[5] = bfbits(h0.y); p0.u[6] = bfbits(h0.z); p0.u[7] = bfbits(h0.w);
            p1.u[0] = bfbits(l1.x); p1.u[1] = bfbits(l1.y); p1.u[2] = bfbits(l1.z); p1.u[3] = bfbits(l1.w);
            p1.u[4] = bfbits(h1.x); p1.u[5] = bfbits(h1.y); p1.u[6] = bfbits(h1.z); p1.u[7] = bfbits(h1.w);
            bf8_t bfr[4];
#pragma unroll
            for (int j = 0; j < 4; ++j) {
                const int row = wc * 64 + j * 16 + c;
                const int sl = (kk * 4 + g) ^ (row & 31);
                bfr[j] = *(const bf8_t*)(Wl + row * 256 + sl * 8);
            }
#pragma unroll
            for (int j = 0; j < 4; ++j) {
                acc[0][j] = MFMA16(p0.v, bfr[j], acc[0][j]);
                acc[1][j] = MFMA16(p1.v, bfr[j], acc[1][j]);
            }
        }
#pragma unroll
        for (int i = 0; i < 2; ++i) {
            const long rbase = m0 + wr * 32 + i * 16 + 4 * g;
#pragma unroll
            for (int j = 0; j < 4; ++j) {
                const int col = n0 + wc * 64 + j * 16 + c;
                const float bv = bias[col];
#pragma unroll
                for (int r = 0; r < 4; ++r) {
                    const long rr = rbase + r;
                    if (rr < MVAL)
                        C[rr * 256 + col] = bfbits(acc[i][j][r] + bv);
                }
            }
        }
    }
}

// ---------------- fp32-A GEMM, reg-staged; A2 added for n0 < addLim (QKV) -----
template<bool OUTBF16>
__global__ __launch_bounds__(256) void gemm_f32a(
    const float* __restrict__ A, const float* __restrict__ A2,
    const unsigned short* __restrict__ W, const float* __restrict__ bias,
    void* __restrict__ C, int M, int N, int K, int addLim)
{
    __shared__ unsigned short As[128 * 32];
    __shared__ unsigned short Ws[128 * 32];
    const int t = threadIdx.x;
    const long m0 = (long)blockIdx.x * 128;
    const int n0 = blockIdx.y * 128;
    const bool useAdd = n0 < addLim;
    const int row0 = t >> 2, cg = t & 3;
    const int cgp = cg ^ ((t >> 2) & 3);
    long ar0 = m0 + row0;        if (ar0 > M - 1) ar0 = M - 1;
    long ar1 = m0 + 64 + row0;   if (ar1 > M - 1) ar1 = M - 1;
    const float* Ap0 = A + ar0 * K + cg * 8;
    const float* Ap1 = A + ar1 * K + cg * 8;
    const float* Bp0 = A2 + ar0 * K + cg * 8;
    const float* Bp1 = A2 + ar1 * K + cg * 8;
    const unsigned short* gw0 = W + (long)(n0 + row0) * K + cgp * 8;
    const unsigned short* gw1 = W + (long)(n0 + 64 + row0) * K + cgp * 8;
    unsigned short* la0 = As + row0 * 32 + ((cg * 8) ^ ((row0 & 3) * 8));
    unsigned short* la1 = la0 + 2048;
    const int lane = t & 63, wave = t >> 6;
    const int c = lane & 15, g = lane >> 4;
    const int wr = wave >> 1, wc = wave & 1;
    const int sws = (g * 8) ^ ((c & 3) * 8);
    f4_t acc[4][4];
#pragma unroll
    for (int i = 0; i < 4; ++i)
#pragma unroll
        for (int j = 0; j < 4; ++j)
            acc[i][j] = f4_t{0.f, 0.f, 0.f, 0.f};

    for (int kb = 0; kb < K; kb += 32) {
        gload16(gw0 + kb, Ws + t * 8);
        gload16(gw1 + kb, Ws + 2048 + t * 8);
        float4 a00 = *(const float4*)(Ap0 + kb);
        float4 a01 = *(const float4*)(Ap0 + kb + 4);
        float4 a10 = *(const float4*)(Ap1 + kb);
        float4 a11 = *(const float4*)(Ap1 + kb + 4);
        if (useAdd) {
            const float4 b00 = *(const float4*)(Bp0 + kb);
            const float4 b01 = *(const float4*)(Bp0 + kb + 4);
            const float4 b10 = *(const float4*)(Bp1 + kb);
            const float4 b11 = *(const float4*)(Bp1 + kb + 4);
            a00.x += b00.x; a00.y += b00.y; a00.z += b00.z; a00.w += b00.w;
            a01.x += b01.x; a01.y += b01.y; a01.z += b01.z; a01.w += b01.w;
            a10.x += b10.x; a10.y += b10.y; a10.z += b10.z; a10.w += b10.w;
            a11.x += b11.x; a11.y += b11.y; a11.z += b11.z; a11.w += b11.w;
        }
        union { bf8_t v; unsigned short u[8]; } p0, p1;
        p0.u[0] = bfbits(a00.x); p0.u[1] = bfbits(a00.y); p0.u[2] = bfbits(a00.z); p0.u[3] = bfbits(a00.w);
        p0.u[4] = bfbits(a01.x); p0.u[5] = bfbits(a01.y); p0.u[6] = bfbits(a01.z); p0.u[7] = bfbits(a01.w);
        p1.u[0] = bfbits(a10.x); p1.u[1] = bfbits(a10.y); p1.u[2] = bfbits(a10.z); p1.u[3] = bfbits(a10.w);
        p1.u[4] = bfbits(a11.x); p1.u[5] = bfbits(a11.y); p1.u[6] = bfbits(a11.z); p1.u[7] = bfbits(a11.w);
        *(bf8_t*)la0 = p0.v;
        *(bf8_t*)la1 = p1.v;
        __syncthreads();
        bf8_t af[4], bfr[4];
#pragma unroll
        for (int i = 0; i < 4; ++i) {
            af[i] = *(const bf8_t*)(As + (wr * 64 + i * 16 + c) * 32 + sws);
            bfr[i] = *(const bf8_t*)(Ws + (wc * 64 + i * 16 + c) * 32 + sws);
        }
#pragma unroll
        for (int i = 0; i < 4; ++i)
#pragma unroll
            for (int j = 0; j < 4; ++j)
                acc[i][j] = MFMA16(af[i], bfr[j], acc[i][j]);
        __syncthreads();
    }

#pragma unroll
    for (int i = 0; i < 4; ++i) {
        const long rbase = m0 + wr * 64 + i * 16 + 4 * g;
#pragma unroll
        for (int j = 0; j < 4; ++j) {
            const int col = n0 + wc * 64 + j * 16 + c;
            const float bv = bias[col];
#pragma unroll
            for (int r = 0; r < 4; ++r) {
                const long rr = rbase + r;
                if (rr < M) {
                    float v = acc[i][j][r] + bv;
                    if (OUTBF16) ((unsigned short*)C)[rr * N + col] = bfbits(v);
                    else         ((float*)C)[rr * N + col] = v;
                }
            }
        }
    }
}

// ---------------- MFMA flash attention (QKV fused rows of 768) ----------------
__global__ __launch_bounds__(256) void attn_mfma(
    const unsigned short* __restrict__ Qb, const unsigned short* __restrict__ Kb,
    const unsigned short* __restrict__ Vb, unsigned short* __restrict__ sa)
{
    __shared__ float smemf[2112];   // 4KB Ks + 4KB Vt; reused as 4x528f O-stage
    unsigned short* Ks = (unsigned short*)smemf;            // [64][32]
    unsigned short* Vt = (unsigned short*)(smemf + 1024);   // [32][64] swizzled
    const int t = threadIdx.x;
    const int wave = t >> 6, lane = t & 63;
    const int g = lane >> 4, c = lane & 15;
    const int b = blockIdx.x >> 3, h = blockIdx.x & 7;
    const int q0 = blockIdx.y * 64 + wave * 16;
    const int q = q0 + c;
    const bool qv = q < NQ_;
    const bf8_t qf = *(const bf8_t*)(Qb + ((long)(qv ? q : 0) * BS_ + b) * QKVS + h * HD_ + 8 * g);

    f4_t acc0 = {0.f, 0.f, 0.f, 0.f}, acc1 = {0.f, 0.f, 0.f, 0.f};
    float m_run = -1e30f, l_run = 0.f;
    const int sk = t >> 2, sd = (t & 3) * 8;

    for (int kc = 0; kc < NQ_; kc += 64) {
        __syncthreads();
        {
            const int key = kc + sk;
            union { bf8_t v; unsigned short u[8]; } kv, vv;
            if (key < NQ_) {
                kv.v = *(const bf8_t*)(Kb + ((long)key * BS_ + b) * QKVS + h * HD_ + sd);
                vv.v = *(const bf8_t*)(Vb + ((long)key * BS_ + b) * QKVS + h * HD_ + sd);
            } else {
#pragma unroll
                for (int u = 0; u < 8; ++u) { kv.u[u] = 0; vv.u[u] = 0; }
            }
            *(bf8_t*)(Ks + sk * 32 + sd) = kv.v;
#pragma unroll
            for (int u = 0; u < 8; ++u) {
                const int r = sd + u;
                Vt[r * 64 + (sk ^ ((r & 7) << 3))] = vv.u[u];
            }
        }
        __syncthreads();

        f4_t s[4];
#pragma unroll
        for (int tt = 0; tt < 4; ++tt) {
            const bf8_t kf = *(const bf8_t*)(Ks + (tt * 16 + c) * 32 + 8 * g);
            f4_t z = {0.f, 0.f, 0.f, 0.f};
            s[tt] = MFMA16(kf, qf, z);
        }
        float sv[16];
#pragma unroll
        for (int tt = 0; tt < 4; ++tt)
#pragma unroll
            for (int r = 0; r < 4; ++r) {
                float x = s[tt][r];
                if (kc + tt * 16 + 4 * g + r >= NQ_) x = -1e30f;
                sv[tt * 4 + r] = x;
            }
        float mloc = sv[0];
#pragma unroll
        for (int i = 1; i < 16; ++i) mloc = fmaxf(mloc, sv[i]);
        mloc = fmaxf(mloc, __shfl_xor(mloc, 16));
        mloc = fmaxf(mloc, __shfl_xor(mloc, 32));
        const float mnew = fmaxf(m_run, mloc);
        const float resc = __expf(m_run - mnew);
        float p[16], ls = 0.f;
#pragma unroll
        for (int i = 0; i < 16; ++i) { p[i] = __expf(sv[i] - mnew); ls += p[i]; }
        ls += __shfl_xor(ls, 16);
        ls += __shfl_xor(ls, 32);
        l_run = l_run * resc + ls;
        m_run = mnew;
#pragma unroll
        for (int r = 0; r < 4; ++r) { acc0[r] *= resc; acc1[r] *= resc; }

        unsigned pk[4][2];
#pragma unroll
        for (int tt = 0; tt < 4; ++tt) {
            pk[tt][0] = (unsigned)bfbits(p[tt * 4 + 0]) | ((unsigned)bfbits(p[tt * 4 + 1]) << 16);
            pk[tt][1] = (unsigned)bfbits(p[tt * 4 + 2]) | ((unsigned)bfbits(p[tt * 4 + 3]) << 16);
        }
        const int srcA = ((g & 1) << 5) + c;
        const int srcB = srcA + 16;
#pragma unroll
        for (int kh = 0; kh < 2; ++kh) {
            const unsigned a0 = __shfl(pk[kh * 2][0], srcA), b0_ = __shfl(pk[kh * 2 + 1][0], srcA);
            const unsigned a1 = __shfl(pk[kh * 2][1], srcA), b1_ = __shfl(pk[kh * 2 + 1][1], srcA);
            const unsigned a2 = __shfl(pk[kh * 2][0], srcB), b2_ = __shfl(pk[kh * 2 + 1][0], srcB);
            const unsigned a3 = __shfl(pk[kh * 2][1], srcB), b3_ = __shfl(pk[kh * 2 + 1][1], srcB);
            union { bf8_t v; unsigned u[4]; } pf;
            const bool hi = (g & 2);
            pf.u[0] = hi ? b0_ : a0; pf.u[1] = hi ? b1_ : a1;
            pf.u[2] = hi ? b2_ : a2; pf.u[3] = hi ? b3_ : a3;
            const int kcol = (kh * 32 + 8 * g) ^ ((c & 7) << 3);
            const bf8_t vf0 = *(const bf8_t*)(Vt + c * 64 + kcol);
            const bf8_t vf1 = *(const bf8_t*)(Vt + (16 + c) * 64 + kcol);
            acc0 = MFMA16(vf0, pf.v, acc0);
            acc1 = MFMA16(vf1, pf.v, acc1);
        }
    }

    __syncthreads();
    const float invl = 1.f / l_run;
    float* O = smemf + wave * 528;
#pragma unroll
    for (int r = 0; r < 4; ++r) {
        O[c * 33 + 4 * g + r] = acc0[r] * invl;
        O[c * 33 + 16 + 4 * g + r] = acc1[r] * invl;
    }
    __syncthreads();
    {
        const int ql = lane >> 2, part = lane & 3;
        const int qg = q0 + ql;
        if (qg < NQ_) {
            union { bf8_t v; unsigned short u[8]; } pk;
#pragma unroll
            for (int u = 0; u < 8; ++u) pk.u[u] = bfbits(O[ql * 33 + part * 8 + u]);
            *(bf8_t*)(sa + ((long)qg * BS_ + b) * D_ + h * HD_ + part * 8) = pk.v;
        }
    }
}

// ---------------- msdeform: softmax + bilinear gather (8B/lane) ----------------
// val layout: native (i,b)-interleaved — val[(cell*8 + b)*256 + d].
__global__ __launch_bounds__(256) void msdeform_kernel(
    const float* __restrict__ oa, const float* __restrict__ refp,
    const unsigned short* __restrict__ val, unsigned short* __restrict__ out)
{
    __shared__ float saw[128];
    __shared__ float redm[8], redi[8];
    __shared__ float swt[128][4];
    __shared__ int sidx[128][4];
    const int bq = blockIdx.x;
    const int b = bq / NQ_, q = bq % NQ_;
    const int t = threadIdx.x;
    if (t < 128) saw[t] = oa[(long)bq * 384 + 256 + t];
    __syncthreads();
    if (t < 8) {
        float mx = -1e30f;
        for (int i = 0; i < 16; ++i) mx = fmaxf(mx, saw[t * 16 + i]);
        float s = 0.f;
        for (int i = 0; i < 16; ++i) s += __expf(saw[t * 16 + i] - mx);
        redm[t] = mx; redi[t] = 1.f / s;
    }
    __syncthreads();
    if (t < 128) {
        const int h = t >> 4, lp = t & 15, l = lp >> 2, p = lp & 3;
        const float aw = __expf(saw[t] - redm[h]) * redi[h];
        const int Wi = (l == 0) ? 100 : (l == 1) ? 50 : (l == 2) ? 25 : 13;
        const int Hi = Wi;
        const int sl = (l == 0) ? 0 : (l == 1) ? 10000 : (l == 2) ? 12500 : 13125;
        const float offx = oa[(long)bq * 384 + h * 32 + l * 8 + p * 2 + 0];
        const float offy = oa[(long)bq * 384 + h * 32 + l * 8 + p * 2 + 1];
        const float refx = refp[(((long)q * BS_ + b) * 4 + l) * 2 + 0];
        const float refy = refp[(((long)q * BS_ + b) * 4 + l) * 2 + 1];
        const float fW = (float)Wi, fH = (float)Hi;
        const float x = (refx + offx / fW) * fW - 0.5f;
        const float y = (refy + offy / fH) * fH - 0.5f;
        const float x0f = floorf(x), y0f = floorf(y);
        const float fx = x - x0f, fy = y - y0f;
        const int ix = (int)x0f, iy = (int)y0f;
        const float wts[4] = {(1.f - fx) * (1.f - fy), fx * (1.f - fy),
                              (1.f - fx) * fy,          fx * fy};
        const int xs[4] = {ix, ix + 1, ix, ix + 1};
        const int ys[4] = {iy, iy, iy + 1, iy + 1};
#pragma unroll
        for (int tap = 0; tap < 4; ++tap) {
            const bool valid = (xs[tap] >= 0) & (xs[tap] < Wi) & (ys[tap] >= 0) & (ys[tap] < Hi);
            const int xc = min(max(xs[tap], 0), Wi - 1);
            const int yc = min(max(ys[tap], 0), Hi - 1);
            swt[t][tap] = valid ? aw * wts[tap] : 0.f;
            sidx[t][tap] = ((sl + yc * Wi + xc) << 3) + b;   // native (i,b) layout
        }
    }
    __syncthreads();
    const int h = t >> 5, r = t & 31, qd = r & 7, s = r >> 3;
    float a0 = 0.f, a1 = 0.f, a2 = 0.f, a3 = 0.f;
#pragma unroll
    for (int i = 0; i < 16; ++i) {
        const int j = h * 16 + i;
        const float wv = swt[j][s];
        const long base = (long)sidx[j][s] * D_ + h * HD_ + qd * 4;
        const uint2 raw = *(const uint2*)(val + base);
        a0 += wv * bf2f((unsigned short)(raw.x & 0xffff));
        a1 += wv * bf2f((unsigned short)(raw.x >> 16));
        a2 += wv * bf2f((unsigned short)(raw.y & 0xffff));
        a3 += wv * bf2f((unsigned short)(raw.y >> 16));
    }
    a0 += __shfl_xor(a0, 8); a0 += __shfl_xor(a0, 16);
    a1 += __shfl_xor(a1, 8); a1 += __shfl_xor(a1, 16);
    a2 += __shfl_xor(a2, 8); a2 += __shfl_xor(a2, 16);
    a3 += __shfl_xor(a3, 8); a3 += __shfl_xor(a3, 16);
    if (s == 0) {
        union { unsigned short u[4]; uint2 w; } pk;
        pk.u[0] = bfbits(a0); pk.u[1] = bfbits(a1); pk.u[2] = bfbits(a2); pk.u[3] = bfbits(a3);
        *(uint2*)(out + (long)bq * D_ + h * HD_ + qd * 4) = pk.w;
    }
}

// ---------------- LayerNorm: out = LN(inA[r] + inB[rb]); optional bf16 out ----
__global__ __launch_bounds__(256) void ln_kernel(
    const float* __restrict__ inA, const float* __restrict__ inB,
    const float* __restrict__ g, const float* __restrict__ be,
    float* __restrict__ out, const float* __restrict__ pos,
    unsigned short* __restrict__ bfOut, int swapB, int bfMode)
{
    const int r = blockIdx.x * 4 + (threadIdx.x >> 6);
    const int lane = threadIdx.x & 63;
    long rb = r;
    if (swapB) rb = (long)(r & 7) * NQ_ + (r >> 3);
    const float4 a4 = *(const float4*)(inA + (long)r * D_ + lane * 4);
    const float4 b4 = *(const float4*)(inB + rb * D_ + lane * 4);
    float x[4] = {a4.x + b4.x, a4.y + b4.y, a4.z + b4.z, a4.w + b4.w};
    float s = x[0] + x[1] + x[2] + x[3];
#pragma unroll
    for (int off = 32; off > 0; off >>= 1) s += __shfl_xor(s, off);
    const float mu = s * (1.f / D_);
    float v = 0.f;
#pragma unroll
    for (int cc = 0; cc < 4; ++cc) { const float dd = x[cc] - mu; v += dd * dd; }
#pragma unroll
    for (int off = 32; off > 0; off >>= 1) v += __shfl_xor(v, off);
    const float rs = rsqrtf(v * (1.f / D_) + 1e-5f);
    const float4 g4 = *(const float4*)(g + lane * 4);
    const float4 e4 = *(const float4*)(be + lane * 4);
    const float gg[4] = {g4.x, g4.y, g4.z, g4.w};
    const float ee[4] = {e4.x, e4.y, e4.z, e4.w};
    float y[4];
#pragma unroll
    for (int cc = 0; cc < 4; ++cc) y[cc] = (x[cc] - mu) * rs * gg[cc] + ee[cc];
    *(float4*)(out + (long)r * D_ + lane * 4) = make_float4(y[0], y[1], y[2], y[3]);
    if (bfMode) {
        float z[4] = {y[0], y[1], y[2], y[3]};
        long er = r;
        if (bfMode == 2) {
            const float4 p4 = *(const float4*)(pos + (long)r * D_ + lane * 4);
            z[0] += p4.x; z[1] += p4.y; z[2] += p4.z; z[3] += p4.w;
            er = (long)(r & 7) * NQ_ + (r >> 3);
        }
        union { unsigned short u[4]; uint2 w; } pk;
        pk.u[0] = bfbits(z[0]); pk.u[1] = bfbits(z[1]);
        pk.u[2] = bfbits(z[2]); pk.u[3] = bfbits(z[3]);
        *(uint2*)(bfOut + er * D_ + lane * 4) = pk.w;
    }
}

// ---------------------------------------------------------------------------
extern "C" void kernel_launch(void* const* d_in, const int* in_sizes, int n_in,
                              void* d_out, int out_size, void* d_ws, size_t ws_size,
                              hipStream_t stream) {
    const float* tgt   = (const float*)d_in[0];
    const float* pos   = (const float*)d_in[1];
    const float* refp  = (const float*)d_in[2];
    const float* mem   = (const float*)d_in[3];
    const float* ipw   = (const float*)d_in[6];
    const float* ipb   = (const float*)d_in[7];
    const float* opw   = (const float*)d_in[8];
    const float* opb   = (const float*)d_in[9];
    const float* sow   = (const float*)d_in[10];
    const float* sob   = (const float*)d_in[11];
    const float* aww   = (const float*)d_in[12];
    const float* awb   = (const float*)d_in[13];
    const float* vpw   = (const float*)d_in[14];
    const float* vpb   = (const float*)d_in[15];
    const float* outpw = (const float*)d_in[16];
    const float* outpb = (const float*)d_in[17];
    const float* l1w   = (const float*)d_in[18];
    const float* l1b   = (const float*)d_in[19];
    const float* l2w   = (const float*)d_in[20];
    const float* l2b   = (const float*)d_in[21];
    const float* n1g = (const float*)d_in[22]; const float* n1be = (const float*)d_in[23];
    const float* n2g = (const float*)d_in[24]; const float* n2be = (const float*)d_in[25];
    const float* n3g = (const float*)d_in[26]; const float* n3be = (const float*)d_in[27];

    // ---- workspace carve-up (no aliasing; ws is ~435MB) ----
    char* wsb = (char*)d_ws;
    auto alloc = [&](size_t bytes) { char* p = wsb; wsb += (bytes + 255) & ~(size_t)255; return p; };
    unsigned short* Wbf       = (unsigned short*)alloc(1015808 * 2);
    float*          biasAll   = (float*)alloc(1152 * 4);
    unsigned short* QKV_bf    = (unsigned short*)alloc((long)MTOK * QKVS * 2);
    unsigned short* sa_bf     = (unsigned short*)alloc(T * 2);
    float*          saproj    = (float*)alloc(T * 4);
    float*          t1        = (float*)alloc(T * 4);
    unsigned short* qplus2_bf = (unsigned short*)alloc(T * 2);
    float*          oa        = (float*)alloc((long)MTOK * 384 * 4);
    unsigned short* sampo_bf  = (unsigned short*)alloc(T * 2);
    float*          ca        = (float*)alloc(T * 4);
    float*          t2        = (float*)alloc(T * 4);
    unsigned short* t2_bf     = (unsigned short*)alloc(T * 2);
    unsigned short* ffnh_bf   = (unsigned short*)alloc((long)MTOK * DFF_ * 2);
    float*          ffno      = (float*)alloc(T * 4);
    unsigned short* val       = (unsigned short*)alloc((long)MVAL * D_ * 2);
    // weight slices inside Wbf
    const unsigned short* wqkv  = Wbf + 0;        // 768 x 256
    const unsigned short* wo    = Wbf + 196608;
    const unsigned short* wsoaw = Wbf + 262144;   // 384 x 256
    const unsigned short* wvp   = Wbf + 360448;
    const unsigned short* wop   = Wbf + 425984;
    const unsigned short* wl1   = Wbf + 491520;
    const unsigned short* wl2   = Wbf + 753664;
    const float* bias_qkv = biasAll;
    const float* bias_oa  = biasAll + 768;

    const dim3 blk(256);
    const dim3 g_m(57, 2);   // 7200 rows, 256 cols (128x128 tiles)

    conv_weights<<<992, blk, 0, stream>>>(ipw, opw, sow, aww, vpw, outpw, l1w, l2w,
                                          ipb, sob, awb, Wbf, biasAll);
    // fused QKV projection: N=768; n<512 uses tgt+pos, n>=512 uses tgt
    gemm_f32a<true><<<dim3(57, 6), blk, 0, stream>>>(tgt, pos, wqkv, bias_qkv, QKV_bf,
                                                     MTOK, QKVS, D_, 512);
    // self-attention (fused QKV rows)
    attn_mfma<<<dim3(64, 15), blk, 0, stream>>>(QKV_bf, QKV_bf + 256, QKV_bf + 512, sa_bf);
    // out_proj
    gemm_mfma<false, false><<<g_m, blk, 0, stream>>>(sa_bf, wo, opb, saproj, MTOK, D_, D_);
    // t1 = LN2(tgt + saproj); qplus2_bf = bf16(t1 + pos) transposed (b,q)
    ln_kernel<<<1800, blk, 0, stream>>>(tgt, saproj, n2g, n2be, t1, pos, qplus2_bf, 0, 2);
    // value projection: W-resident barrier-free, identity row map
    gemm_vdir<<<dim3(256, 2), blk, 0, stream>>>(mem, wvp, vpb, val);
    // fused samp_off + attn_w (N=384, f32 out)
    gemm_mfma<false, false><<<dim3(57, 3), blk, 0, stream>>>(qplus2_bf, wsoaw, bias_oa, oa, MTOK, 384, D_);
    // deformable sampling (native-layout val)
    msdeform_kernel<<<7200, blk, 0, stream>>>(oa, refp, val, sampo_bf);
    // output projection
    gemm_mfma<false, false><<<g_m, blk, 0, stream>>>(sampo_bf, wop, outpb, ca, MTOK, D_, D_);
    // t2 = LN1(t1 + ca^T) + bf16 copy
    ln_kernel<<<1800, blk, 0, stream>>>(t1, ca, n1g, n1be, t2, nullptr, t2_bf, 1, 1);
    // FFN
    gemm_mfma<true, true><<<dim3(57, 8), blk, 0, stream>>>(t2_bf, wl1, l1b, ffnh_bf, MTOK, DFF_, D_);
    gemm_mfma<false, false><<<g_m, blk, 0, stream>>>(ffnh_bf, wl2, l2b, ffno, MTOK, D_, DFF_);
    // out = LN3(t2 + ffn)
    ln_kernel<<<1800, blk, 0, stream>>>(t2, ffno, n3g, n3be, (float*)d_out, nullptr, nullptr, 0, 0);
}

// Round 15
// 235.659 us; speedup vs baseline: 1.1300x; 1.1300x over previous
//
#include <hip/hip_runtime.h>
#include <hip/hip_bf16.h>

// ---------------------------------------------------------------------------
// DeformableTransformerDecoderLayer on MI355X — round 15 (consolidation):
//  - value GEMM: back to round-13 gemm_f32d (identity map, global_load_lds,
//    BK=64) — best measured (77us). NEW: LDS-staged C epilogue (coalesced
//    256B-run writes instead of 32B scattered partial lines).
//  - keep QKV fused N=768 GEMM (round-14, ~8us win).
//  - per-lane A->reg variants abandoned: MFMA A-layout puts lanes on rows
//    (1KB stride) -> inherently uncoalesced (wres/vdir both 0.5-1.1 TB/s).
// ---------------------------------------------------------------------------

namespace {
constexpr int D_ = 256;
constexpr int NQ_ = 900;
constexpr int BS_ = 8;
constexpr int NH_ = 8;
constexpr int HD_ = 32;
constexpr int DFF_ = 1024;
constexpr int MTOK = NQ_ * BS_;       // 7200
constexpr int LMEM_ = 13294;
constexpr long T = (long)MTOK * D_;   // 1843200
constexpr float QSC = 0.17677669529663687f;  // 1/sqrt(32)
constexpr int QKVS = 768;             // fused QKV row stride
constexpr int MVAL = BS_ * LMEM_;     // 106352
}

typedef __attribute__((ext_vector_type(8))) short bf8_t;
typedef __attribute__((ext_vector_type(4))) float f4_t;

#define MFMA16(a, b, c) __builtin_amdgcn_mfma_f32_16x16x32_bf16((a), (b), (c), 0, 0, 0)

__device__ __forceinline__ unsigned short bfbits(float x) {
    union { __hip_bfloat16 h; unsigned short u; } cv;
    cv.h = __float2bfloat16(x);
    return cv.u;
}
__device__ __forceinline__ float bf2f(unsigned short u) {
    union { float f; unsigned v; } cv;
    cv.v = ((unsigned)u) << 16;
    return cv.f;
}

__device__ __forceinline__ void gload16(const unsigned short* g, unsigned short* l) {
    __builtin_amdgcn_global_load_lds(
        (const __attribute__((address_space(1))) unsigned int*)(g),
        (__attribute__((address_space(3))) unsigned int*)(l), 16, 0, 0);
}
__device__ __forceinline__ void gload16f(const float* g, float* l) {
    __builtin_amdgcn_global_load_lds(
        (const __attribute__((address_space(1))) unsigned int*)(g),
        (__attribute__((address_space(3))) unsigned int*)(l), 16, 0, 0);
}

// fused weight conversion; Wq scaled by QSC; biasAll = [qkv bias 768 | oa bias 384]
__global__ void conv_weights(
    const float* __restrict__ ipw, const float* __restrict__ opw,
    const float* __restrict__ sow, const float* __restrict__ aww,
    const float* __restrict__ vpw, const float* __restrict__ outpw,
    const float* __restrict__ l1w, const float* __restrict__ l2w,
    const float* __restrict__ ipb, const float* __restrict__ sob,
    const float* __restrict__ awb,
    unsigned short* __restrict__ Wbf, float* __restrict__ biasAll)
{
    if (blockIdx.x == 0) {
        for (int j = threadIdx.x; j < 768; j += 256)
            biasAll[j] = (j < 256) ? ipb[j] * QSC : ipb[j];
        for (int j = threadIdx.x; j < 384; j += 256)
            biasAll[768 + j] = (j < 256) ? sob[j] : awb[j - 256];
    }
    const long idx4 = (long)blockIdx.x * 256 + threadIdx.x;
    if (idx4 >= 253952) return;
    const long e = idx4 * 4;
    const float* src; long off; float sc = 1.f;
    if (e < 196608)      { src = ipw;   off = 0;      if (e < 65536) sc = QSC; }
    else if (e < 262144) { src = opw;   off = 196608; }
    else if (e < 327680) { src = sow;   off = 262144; }
    else if (e < 360448) { src = aww;   off = 327680; }
    else if (e < 425984) { src = vpw;   off = 360448; }
    else if (e < 491520) { src = outpw; off = 425984; }
    else if (e < 753664) { src = l1w;   off = 491520; }
    else                 { src = l2w;   off = 753664; }
    const float4 v = *(const float4*)(src + (e - off));
    union { unsigned short u[4]; uint2 w; } pk;
    pk.u[0] = bfbits(v.x * sc); pk.u[1] = bfbits(v.y * sc);
    pk.u[2] = bfbits(v.z * sc); pk.u[3] = bfbits(v.w * sc);
    *(uint2*)(Wbf + e) = pk.w;
}

// ---------------- bf16-A MFMA GEMM (m97 single-buffer, swizzled reads) --------
template<bool RELU, bool OUTBF16>
__global__ __launch_bounds__(256) void gemm_mfma(
    const unsigned short* __restrict__ A, const unsigned short* __restrict__ W,
    const float* __restrict__ bias, void* __restrict__ C, int M, int N, int K)
{
    __shared__ unsigned short As[128 * 32];
    __shared__ unsigned short Ws[128 * 32];
    const int t = threadIdx.x;
    const long m0 = (long)blockIdx.x * 128;
    const int n0 = blockIdx.y * 128;
    const int row0 = t >> 2;
    const int cgp = (t & 3) ^ ((t >> 2) & 3);
    long ar0 = m0 + row0;        if (ar0 > M - 1) ar0 = M - 1;
    long ar1 = m0 + 64 + row0;   if (ar1 > M - 1) ar1 = M - 1;
    const unsigned short* ga0 = A + ar0 * K + cgp * 8;
    const unsigned short* ga1 = A + ar1 * K + cgp * 8;
    const unsigned short* gw0 = W + (long)(n0 + row0) * K + cgp * 8;
    const unsigned short* gw1 = W + (long)(n0 + 64 + row0) * K + cgp * 8;
    const int lane = t & 63, wave = t >> 6;
    const int c = lane & 15, g = lane >> 4;
    const int wr = wave >> 1, wc = wave & 1;
    const int sws = (g * 8) ^ ((c & 3) * 8);
    f4_t acc[4][4];
#pragma unroll
    for (int i = 0; i < 4; ++i)
#pragma unroll
        for (int j = 0; j < 4; ++j)
            acc[i][j] = f4_t{0.f, 0.f, 0.f, 0.f};

    for (int kb = 0; kb < K; kb += 32) {
        gload16(ga0 + kb, As + t * 8);
        gload16(ga1 + kb, As + 2048 + t * 8);
        gload16(gw0 + kb, Ws + t * 8);
        gload16(gw1 + kb, Ws + 2048 + t * 8);
        __syncthreads();
        bf8_t af[4], bfr[4];
#pragma unroll
        for (int i = 0; i < 4; ++i) {
            af[i] = *(const bf8_t*)(As + (wr * 64 + i * 16 + c) * 32 + sws);
            bfr[i] = *(const bf8_t*)(Ws + (wc * 64 + i * 16 + c) * 32 + sws);
        }
#pragma unroll
        for (int i = 0; i < 4; ++i)
#pragma unroll
            for (int j = 0; j < 4; ++j)
                acc[i][j] = MFMA16(af[i], bfr[j], acc[i][j]);
        __syncthreads();
    }

#pragma unroll
    for (int i = 0; i < 4; ++i) {
        const long rbase = m0 + wr * 64 + i * 16 + 4 * g;
#pragma unroll
        for (int j = 0; j < 4; ++j) {
            const int col = n0 + wc * 64 + j * 16 + c;
            const float bv = bias[col];
#pragma unroll
            for (int r = 0; r < 4; ++r) {
                const long rr = rbase + r;
                if (rr < M) {
                    float v = acc[i][j][r] + bv;
                    if (RELU) v = fmaxf(v, 0.f);
                    if (OUTBF16) ((unsigned short*)C)[rr * N + col] = bfbits(v);
                    else         ((float*)C)[rr * N + col] = v;
                }
            }
        }
    }
}

// ---------------- value GEMM: fp32-A identity map, BK=64, LDS C-epilogue ------
__global__ __launch_bounds__(256) void gemm_f32d(
    const float* __restrict__ A, const unsigned short* __restrict__ W,
    const float* __restrict__ bias, unsigned short* __restrict__ C,
    int M, int N, int K)
{
    __shared__ float Asf[64 * 64];          // 16KB (epilogue reuses as C stage)
    __shared__ unsigned short Ws[128 * 64]; // 16KB
    const int t = threadIdx.x;
    const long m0 = (long)blockIdx.x * 64;
    const int n0 = blockIdx.y * 128;
    const float* gA[4];
#pragma unroll
    for (int l = 0; l < 4; ++l) {
        int r = (int)m0 + l * 16 + (t >> 4); if (r > M - 1) r = M - 1;
        const int sp = (t & 15) ^ ((t >> 4) & 15);
        gA[l] = A + (long)r * K + sp * 4;
    }
    const unsigned short* gW[4];
#pragma unroll
    for (int l = 0; l < 4; ++l) {
        const int r = l * 32 + (t >> 3);
        const int sp = (t & 7) ^ (r & 7);
        gW[l] = W + (long)(n0 + r) * K + sp * 8;
    }
    const int lane = t & 63, wave = t >> 6;
    const int c = lane & 15, g = lane >> 4;
    const int wr = wave >> 1, wc = wave & 1;
    f4_t acc[2][4];
#pragma unroll
    for (int i = 0; i < 2; ++i)
#pragma unroll
        for (int j = 0; j < 4; ++j)
            acc[i][j] = f4_t{0.f, 0.f, 0.f, 0.f};

    for (int kb = 0; kb < K; kb += 64) {
#pragma unroll
        for (int l = 0; l < 4; ++l) gload16f(gA[l] + kb, Asf + l * 1024 + t * 4);
#pragma unroll
        for (int l = 0; l < 4; ++l) gload16(gW[l] + kb, Ws + l * 2048 + t * 8);
        __syncthreads();
#pragma unroll
        for (int s = 0; s < 2; ++s) {
            bf8_t af[2], bfr[4];
#pragma unroll
            for (int i = 0; i < 2; ++i) {
                const int row = wr * 32 + i * 16 + c;
                const int sl0 = (s * 8 + 2 * g) ^ (row & 15);
                const int sl1 = (s * 8 + 2 * g + 1) ^ (row & 15);
                const f4_t lo = *(const f4_t*)(Asf + row * 64 + sl0 * 4);
                const f4_t hi = *(const f4_t*)(Asf + row * 64 + sl1 * 4);
                union { bf8_t v; unsigned short u[8]; } pk;
                pk.u[0] = bfbits(lo[0]); pk.u[1] = bfbits(lo[1]);
                pk.u[2] = bfbits(lo[2]); pk.u[3] = bfbits(lo[3]);
                pk.u[4] = bfbits(hi[0]); pk.u[5] = bfbits(hi[1]);
                pk.u[6] = bfbits(hi[2]); pk.u[7] = bfbits(hi[3]);
                af[i] = pk.v;
            }
#pragma unroll
            for (int j = 0; j < 4; ++j) {
                const int row = wc * 64 + j * 16 + c;
                const int sl = (s * 4 + g) ^ (row & 7);
                bfr[j] = *(const bf8_t*)(Ws + row * 64 + sl * 8);
            }
#pragma unroll
            for (int i = 0; i < 2; ++i)
#pragma unroll
                for (int j = 0; j < 4; ++j)
                    acc[i][j] = MFMA16(af[i], bfr[j], acc[i][j]);
        }
        __syncthreads();
    }

    // ---- epilogue: stage C tile (64x128 bf16 = 16KB) in Asf, write coalesced
    unsigned short* Cl = (unsigned short*)Asf;
#pragma unroll
    for (int i = 0; i < 2; ++i) {
        const int rloc = wr * 32 + i * 16 + 4 * g;
#pragma unroll
        for (int j = 0; j < 4; ++j) {
            const int col = wc * 64 + j * 16 + c;
            const float bv = bias[n0 + col];
#pragma unroll
            for (int r = 0; r < 4; ++r)
                Cl[(rloc + r) * 128 + col] = bfbits(acc[i][j][r] + bv);
        }
    }
    __syncthreads();
    {
        const int row = t >> 2, seg = t & 3;      // 4 lanes/row, 64B each
        const long rr = m0 + row;
        if (rr < M) {
            const uint4* src = (const uint4*)(Cl + row * 128 + seg * 32);
            uint4* dst = (uint4*)(C + rr * N + n0 + seg * 32);
            dst[0] = src[0]; dst[1] = src[1]; dst[2] = src[2]; dst[3] = src[3];
        }
    }
}

// ---------------- fp32-A GEMM, reg-staged; A2 added for n0 < addLim (QKV) -----
template<bool OUTBF16>
__global__ __launch_bounds__(256) void gemm_f32a(
    const float* __restrict__ A, const float* __restrict__ A2,
    const unsigned short* __restrict__ W, const float* __restrict__ bias,
    void* __restrict__ C, int M, int N, int K, int addLim)
{
    __shared__ unsigned short As[128 * 32];
    __shared__ unsigned short Ws[128 * 32];
    const int t = threadIdx.x;
    const long m0 = (long)blockIdx.x * 128;
    const int n0 = blockIdx.y * 128;
    const bool useAdd = n0 < addLim;
    const int row0 = t >> 2, cg = t & 3;
    const int cgp = cg ^ ((t >> 2) & 3);
    long ar0 = m0 + row0;        if (ar0 > M - 1) ar0 = M - 1;
    long ar1 = m0 + 64 + row0;   if (ar1 > M - 1) ar1 = M - 1;
    const float* Ap0 = A + ar0 * K + cg * 8;
    const float* Ap1 = A + ar1 * K + cg * 8;
    const float* Bp0 = A2 + ar0 * K + cg * 8;
    const float* Bp1 = A2 + ar1 * K + cg * 8;
    const unsigned short* gw0 = W + (long)(n0 + row0) * K + cgp * 8;
    const unsigned short* gw1 = W + (long)(n0 + 64 + row0) * K + cgp * 8;
    unsigned short* la0 = As + row0 * 32 + ((cg * 8) ^ ((row0 & 3) * 8));
    unsigned short* la1 = la0 + 2048;
    const int lane = t & 63, wave = t >> 6;
    const int c = lane & 15, g = lane >> 4;
    const int wr = wave >> 1, wc = wave & 1;
    const int sws = (g * 8) ^ ((c & 3) * 8);
    f4_t acc[4][4];
#pragma unroll
    for (int i = 0; i < 4; ++i)
#pragma unroll
        for (int j = 0; j < 4; ++j)
            acc[i][j] = f4_t{0.f, 0.f, 0.f, 0.f};

    for (int kb = 0; kb < K; kb += 32) {
        gload16(gw0 + kb, Ws + t * 8);
        gload16(gw1 + kb, Ws + 2048 + t * 8);
        float4 a00 = *(const float4*)(Ap0 + kb);
        float4 a01 = *(const float4*)(Ap0 + kb + 4);
        float4 a10 = *(const float4*)(Ap1 + kb);
        float4 a11 = *(const float4*)(Ap1 + kb + 4);
        if (useAdd) {
            const float4 b00 = *(const float4*)(Bp0 + kb);
            const float4 b01 = *(const float4*)(Bp0 + kb + 4);
            const float4 b10 = *(const float4*)(Bp1 + kb);
            const float4 b11 = *(const float4*)(Bp1 + kb + 4);
            a00.x += b00.x; a00.y += b00.y; a00.z += b00.z; a00.w += b00.w;
            a01.x += b01.x; a01.y += b01.y; a01.z += b01.z; a01.w += b01.w;
            a10.x += b10.x; a10.y += b10.y; a10.z += b10.z; a10.w += b10.w;
            a11.x += b11.x; a11.y += b11.y; a11.z += b11.z; a11.w += b11.w;
        }
        union { bf8_t v; unsigned short u[8]; } p0, p1;
        p0.u[0] = bfbits(a00.x); p0.u[1] = bfbits(a00.y); p0.u[2] = bfbits(a00.z); p0.u[3] = bfbits(a00.w);
        p0.u[4] = bfbits(a01.x); p0.u[5] = bfbits(a01.y); p0.u[6] = bfbits(a01.z); p0.u[7] = bfbits(a01.w);
        p1.u[0] = bfbits(a10.x); p1.u[1] = bfbits(a10.y); p1.u[2] = bfbits(a10.z); p1.u[3] = bfbits(a10.w);
        p1.u[4] = bfbits(a11.x); p1.u[5] = bfbits(a11.y); p1.u[6] = bfbits(a11.z); p1.u[7] = bfbits(a11.w);
        *(bf8_t*)la0 = p0.v;
        *(bf8_t*)la1 = p1.v;
        __syncthreads();
        bf8_t af[4], bfr[4];
#pragma unroll
        for (int i = 0; i < 4; ++i) {
            af[i] = *(const bf8_t*)(As + (wr * 64 + i * 16 + c) * 32 + sws);
            bfr[i] = *(const bf8_t*)(Ws + (wc * 64 + i * 16 + c) * 32 + sws);
        }
#pragma unroll
        for (int i = 0; i < 4; ++i)
#pragma unroll
            for (int j = 0; j < 4; ++j)
                acc[i][j] = MFMA16(af[i], bfr[j], acc[i][j]);
        __syncthreads();
    }

#pragma unroll
    for (int i = 0; i < 4; ++i) {
        const long rbase = m0 + wr * 64 + i * 16 + 4 * g;
#pragma unroll
        for (int j = 0; j < 4; ++j) {
            const int col = n0 + wc * 64 + j * 16 + c;
            const float bv = bias[col];
#pragma unroll
            for (int r = 0; r < 4; ++r) {
                const long rr = rbase + r;
                if (rr < M) {
                    float v = acc[i][j][r] + bv;
                    if (OUTBF16) ((unsigned short*)C)[rr * N + col] = bfbits(v);
                    else         ((float*)C)[rr * N + col] = v;
                }
            }
        }
    }
}

// ---------------- MFMA flash attention (QKV fused rows of 768) ----------------
__global__ __launch_bounds__(256) void attn_mfma(
    const unsigned short* __restrict__ Qb, const unsigned short* __restrict__ Kb,
    const unsigned short* __restrict__ Vb, unsigned short* __restrict__ sa)
{
    __shared__ float smemf[2112];   // 4KB Ks + 4KB Vt; reused as 4x528f O-stage
    unsigned short* Ks = (unsigned short*)smemf;            // [64][32]
    unsigned short* Vt = (unsigned short*)(smemf + 1024);   // [32][64] swizzled
    const int t = threadIdx.x;
    const int wave = t >> 6, lane = t & 63;
    const int g = lane >> 4, c = lane & 15;
    const int b = blockIdx.x >> 3, h = blockIdx.x & 7;
    const int q0 = blockIdx.y * 64 + wave * 16;
    const int q = q0 + c;
    const bool qv = q < NQ_;
    const bf8_t qf = *(const bf8_t*)(Qb + ((long)(qv ? q : 0) * BS_ + b) * QKVS + h * HD_ + 8 * g);

    f4_t acc0 = {0.f, 0.f, 0.f, 0.f}, acc1 = {0.f, 0.f, 0.f, 0.f};
    float m_run = -1e30f, l_run = 0.f;
    const int sk = t >> 2, sd = (t & 3) * 8;

    for (int kc = 0; kc < NQ_; kc += 64) {
        __syncthreads();
        {
            const int key = kc + sk;
            union { bf8_t v; unsigned short u[8]; } kv, vv;
            if (key < NQ_) {
                kv.v = *(const bf8_t*)(Kb + ((long)key * BS_ + b) * QKVS + h * HD_ + sd);
                vv.v = *(const bf8_t*)(Vb + ((long)key * BS_ + b) * QKVS + h * HD_ + sd);
            } else {
#pragma unroll
                for (int u = 0; u < 8; ++u) { kv.u[u] = 0; vv.u[u] = 0; }
            }
            *(bf8_t*)(Ks + sk * 32 + sd) = kv.v;
#pragma unroll
            for (int u = 0; u < 8; ++u) {
                const int r = sd + u;
                Vt[r * 64 + (sk ^ ((r & 7) << 3))] = vv.u[u];
            }
        }
        __syncthreads();

        f4_t s[4];
#pragma unroll
        for (int tt = 0; tt < 4; ++tt) {
            const bf8_t kf = *(const bf8_t*)(Ks + (tt * 16 + c) * 32 + 8 * g);
            f4_t z = {0.f, 0.f, 0.f, 0.f};
            s[tt] = MFMA16(kf, qf, z);
        }
        float sv[16];
#pragma unroll
        for (int tt = 0; tt < 4; ++tt)
#pragma unroll
            for (int r = 0; r < 4; ++r) {
                float x = s[tt][r];
                if (kc + tt * 16 + 4 * g + r >= NQ_) x = -1e30f;
                sv[tt * 4 + r] = x;
            }
        float mloc = sv[0];
#pragma unroll
        for (int i = 1; i < 16; ++i) mloc = fmaxf(mloc, sv[i]);
        mloc = fmaxf(mloc, __shfl_xor(mloc, 16));
        mloc = fmaxf(mloc, __shfl_xor(mloc, 32));
        const float mnew = fmaxf(m_run, mloc);
        const float resc = __expf(m_run - mnew);
        float p[16], ls = 0.f;
#pragma unroll
        for (int i = 0; i < 16; ++i) { p[i] = __expf(sv[i] - mnew); ls += p[i]; }
        ls += __shfl_xor(ls, 16);
        ls += __shfl_xor(ls, 32);
        l_run = l_run * resc + ls;
        m_run = mnew;
#pragma unroll
        for (int r = 0; r < 4; ++r) { acc0[r] *= resc; acc1[r] *= resc; }

        unsigned pk[4][2];
#pragma unroll
        for (int tt = 0; tt < 4; ++tt) {
            pk[tt][0] = (unsigned)bfbits(p[tt * 4 + 0]) | ((unsigned)bfbits(p[tt * 4 + 1]) << 16);
            pk[tt][1] = (unsigned)bfbits(p[tt * 4 + 2]) | ((unsigned)bfbits(p[tt * 4 + 3]) << 16);
        }
        const int srcA = ((g & 1) << 5) + c;
        const int srcB = srcA + 16;
#pragma unroll
        for (int kh = 0; kh < 2; ++kh) {
            const unsigned a0 = __shfl(pk[kh * 2][0], srcA), b0_ = __shfl(pk[kh * 2 + 1][0], srcA);
            const unsigned a1 = __shfl(pk[kh * 2][1], srcA), b1_ = __shfl(pk[kh * 2 + 1][1], srcA);
            const unsigned a2 = __shfl(pk[kh * 2][0], srcB), b2_ = __shfl(pk[kh * 2 + 1][0], srcB);
            const unsigned a3 = __shfl(pk[kh * 2][1], srcB), b3_ = __shfl(pk[kh * 2 + 1][1], srcB);
            union { bf8_t v; unsigned u[4]; } pf;
            const bool hi = (g & 2);
            pf.u[0] = hi ? b0_ : a0; pf.u[1] = hi ? b1_ : a1;
            pf.u[2] = hi ? b2_ : a2; pf.u[3] = hi ? b3_ : a3;
            const int kcol = (kh * 32 + 8 * g) ^ ((c & 7) << 3);
            const bf8_t vf0 = *(const bf8_t*)(Vt + c * 64 + kcol);
            const bf8_t vf1 = *(const bf8_t*)(Vt + (16 + c) * 64 + kcol);
            acc0 = MFMA16(vf0, pf.v, acc0);
            acc1 = MFMA16(vf1, pf.v, acc1);
        }
    }

    __syncthreads();
    const float invl = 1.f / l_run;
    float* O = smemf + wave * 528;
#pragma unroll
    for (int r = 0; r < 4; ++r) {
        O[c * 33 + 4 * g + r] = acc0[r] * invl;
        O[c * 33 + 16 + 4 * g + r] = acc1[r] * invl;
    }
    __syncthreads();
    {
        const int ql = lane >> 2, part = lane & 3;
        const int qg = q0 + ql;
        if (qg < NQ_) {
            union { bf8_t v; unsigned short u[8]; } pk;
#pragma unroll
            for (int u = 0; u < 8; ++u) pk.u[u] = bfbits(O[ql * 33 + part * 8 + u]);
            *(bf8_t*)(sa + ((long)qg * BS_ + b) * D_ + h * HD_ + part * 8) = pk.v;
        }
    }
}

// ---------------- msdeform: softmax + bilinear gather (8B/lane) ----------------
// val layout: native (i,b)-interleaved — val[(cell*8 + b)*256 + d].
__global__ __launch_bounds__(256) void msdeform_kernel(
    const float* __restrict__ oa, const float* __restrict__ refp,
    const unsigned short* __restrict__ val, unsigned short* __restrict__ out)
{
    __shared__ float saw[128];
    __shared__ float redm[8], redi[8];
    __shared__ float swt[128][4];
    __shared__ int sidx[128][4];
    const int bq = blockIdx.x;
    const int b = bq / NQ_, q = bq % NQ_;
    const int t = threadIdx.x;
    if (t < 128) saw[t] = oa[(long)bq * 384 + 256 + t];
    __syncthreads();
    if (t < 8) {
        float mx = -1e30f;
        for (int i = 0; i < 16; ++i) mx = fmaxf(mx, saw[t * 16 + i]);
        float s = 0.f;
        for (int i = 0; i < 16; ++i) s += __expf(saw[t * 16 + i] - mx);
        redm[t] = mx; redi[t] = 1.f / s;
    }
    __syncthreads();
    if (t < 128) {
        const int h = t >> 4, lp = t & 15, l = lp >> 2, p = lp & 3;
        const float aw = __expf(saw[t] - redm[h]) * redi[h];
        const int Wi = (l == 0) ? 100 : (l == 1) ? 50 : (l == 2) ? 25 : 13;
        const int Hi = Wi;
        const int sl = (l == 0) ? 0 : (l == 1) ? 10000 : (l == 2) ? 12500 : 13125;
        const float offx = oa[(long)bq * 384 + h * 32 + l * 8 + p * 2 + 0];
        const float offy = oa[(long)bq * 384 + h * 32 + l * 8 + p * 2 + 1];
        const float refx = refp[(((long)q * BS_ + b) * 4 + l) * 2 + 0];
        const float refy = refp[(((long)q * BS_ + b) * 4 + l) * 2 + 1];
        const float fW = (float)Wi, fH = (float)Hi;
        const float x = (refx + offx / fW) * fW - 0.5f;
        const float y = (refy + offy / fH) * fH - 0.5f;
        const float x0f = floorf(x), y0f = floorf(y);
        const float fx = x - x0f, fy = y - y0f;
        const int ix = (int)x0f, iy = (int)y0f;
        const float wts[4] = {(1.f - fx) * (1.f - fy), fx * (1.f - fy),
                              (1.f - fx) * fy,          fx * fy};
        const int xs[4] = {ix, ix + 1, ix, ix + 1};
        const int ys[4] = {iy, iy, iy + 1, iy + 1};
#pragma unroll
        for (int tap = 0; tap < 4; ++tap) {
            const bool valid = (xs[tap] >= 0) & (xs[tap] < Wi) & (ys[tap] >= 0) & (ys[tap] < Hi);
            const int xc = min(max(xs[tap], 0), Wi - 1);
            const int yc = min(max(ys[tap], 0), Hi - 1);
            swt[t][tap] = valid ? aw * wts[tap] : 0.f;
            sidx[t][tap] = ((sl + yc * Wi + xc) << 3) + b;   // native (i,b) layout
        }
    }
    __syncthreads();
    const int h = t >> 5, r = t & 31, qd = r & 7, s = r >> 3;
    float a0 = 0.f, a1 = 0.f, a2 = 0.f, a3 = 0.f;
#pragma unroll
    for (int i = 0; i < 16; ++i) {
        const int j = h * 16 + i;
        const float wv = swt[j][s];
        const long base = (long)sidx[j][s] * D_ + h * HD_ + qd * 4;
        const uint2 raw = *(const uint2*)(val + base);
        a0 += wv * bf2f((unsigned short)(raw.x & 0xffff));
        a1 += wv * bf2f((unsigned short)(raw.x >> 16));
        a2 += wv * bf2f((unsigned short)(raw.y & 0xffff));
        a3 += wv * bf2f((unsigned short)(raw.y >> 16));
    }
    a0 += __shfl_xor(a0, 8); a0 += __shfl_xor(a0, 16);
    a1 += __shfl_xor(a1, 8); a1 += __shfl_xor(a1, 16);
    a2 += __shfl_xor(a2, 8); a2 += __shfl_xor(a2, 16);
    a3 += __shfl_xor(a3, 8); a3 += __shfl_xor(a3, 16);
    if (s == 0) {
        union { unsigned short u[4]; uint2 w; } pk;
        pk.u[0] = bfbits(a0); pk.u[1] = bfbits(a1); pk.u[2] = bfbits(a2); pk.u[3] = bfbits(a3);
        *(uint2*)(out + (long)bq * D_ + h * HD_ + qd * 4) = pk.w;
    }
}

// ---------------- LayerNorm: out = LN(inA[r] + inB[rb]); optional bf16 out ----
__global__ __launch_bounds__(256) void ln_kernel(
    const float* __restrict__ inA, const float* __restrict__ inB,
    const float* __restrict__ g, const float* __restrict__ be,
    float* __restrict__ out, const float* __restrict__ pos,
    unsigned short* __restrict__ bfOut, int swapB, int bfMode)
{
    const int r = blockIdx.x * 4 + (threadIdx.x >> 6);
    const int lane = threadIdx.x & 63;
    long rb = r;
    if (swapB) rb = (long)(r & 7) * NQ_ + (r >> 3);
    const float4 a4 = *(const float4*)(inA + (long)r * D_ + lane * 4);
    const float4 b4 = *(const float4*)(inB + rb * D_ + lane * 4);
    float x[4] = {a4.x + b4.x, a4.y + b4.y, a4.z + b4.z, a4.w + b4.w};
    float s = x[0] + x[1] + x[2] + x[3];
#pragma unroll
    for (int off = 32; off > 0; off >>= 1) s += __shfl_xor(s, off);
    const float mu = s * (1.f / D_);
    float v = 0.f;
#pragma unroll
    for (int cc = 0; cc < 4; ++cc) { const float dd = x[cc] - mu; v += dd * dd; }
#pragma unroll
    for (int off = 32; off > 0; off >>= 1) v += __shfl_xor(v, off);
    const float rs = rsqrtf(v * (1.f / D_) + 1e-5f);
    const float4 g4 = *(const float4*)(g + lane * 4);
    const float4 e4 = *(const float4*)(be + lane * 4);
    const float gg[4] = {g4.x, g4.y, g4.z, g4.w};
    const float ee[4] = {e4.x, e4.y, e4.z, e4.w};
    float y[4];
#pragma unroll
    for (int cc = 0; cc < 4; ++cc) y[cc] = (x[cc] - mu) * rs * gg[cc] + ee[cc];
    *(float4*)(out + (long)r * D_ + lane * 4) = make_float4(y[0], y[1], y[2], y[3]);
    if (bfMode) {
        float z[4] = {y[0], y[1], y[2], y[3]};
        long er = r;
        if (bfMode == 2) {
            const float4 p4 = *(const float4*)(pos + (long)r * D_ + lane * 4);
            z[0] += p4.x; z[1] += p4.y; z[2] += p4.z; z[3] += p4.w;
            er = (long)(r & 7) * NQ_ + (r >> 3);
        }
        union { unsigned short u[4]; uint2 w; } pk;
        pk.u[0] = bfbits(z[0]); pk.u[1] = bfbits(z[1]);
        pk.u[2] = bfbits(z[2]); pk.u[3] = bfbits(z[3]);
        *(uint2*)(bfOut + er * D_ + lane * 4) = pk.w;
    }
}

// ---------------------------------------------------------------------------
extern "C" void kernel_launch(void* const* d_in, const int* in_sizes, int n_in,
                              void* d_out, int out_size, void* d_ws, size_t ws_size,
                              hipStream_t stream) {
    const float* tgt   = (const float*)d_in[0];
    const float* pos   = (const float*)d_in[1];
    const float* refp  = (const float*)d_in[2];
    const float* mem   = (const float*)d_in[3];
    const float* ipw   = (const float*)d_in[6];
    const float* ipb   = (const float*)d_in[7];
    const float* opw   = (const float*)d_in[8];
    const float* opb   = (const float*)d_in[9];
    const float* sow   = (const float*)d_in[10];
    const float* sob   = (const float*)d_in[11];
    const float* aww   = (const float*)d_in[12];
    const float* awb   = (const float*)d_in[13];
    const float* vpw   = (const float*)d_in[14];
    const float* vpb   = (const float*)d_in[15];
    const float* outpw = (const float*)d_in[16];
    const float* outpb = (const float*)d_in[17];
    const float* l1w   = (const float*)d_in[18];
    const float* l1b   = (const float*)d_in[19];
    const float* l2w   = (const float*)d_in[20];
    const float* l2b   = (const float*)d_in[21];
    const float* n1g = (const float*)d_in[22]; const float* n1be = (const float*)d_in[23];
    const float* n2g = (const float*)d_in[24]; const float* n2be = (const float*)d_in[25];
    const float* n3g = (const float*)d_in[26]; const float* n3be = (const float*)d_in[27];

    // ---- workspace carve-up (no aliasing; ws is ~435MB) ----
    char* wsb = (char*)d_ws;
    auto alloc = [&](size_t bytes) { char* p = wsb; wsb += (bytes + 255) & ~(size_t)255; return p; };
    unsigned short* Wbf       = (unsigned short*)alloc(1015808 * 2);
    float*          biasAll   = (float*)alloc(1152 * 4);
    unsigned short* QKV_bf    = (unsigned short*)alloc((long)MTOK * QKVS * 2);
    unsigned short* sa_bf     = (unsigned short*)alloc(T * 2);
    float*          saproj    = (float*)alloc(T * 4);
    float*          t1        = (float*)alloc(T * 4);
    unsigned short* qplus2_bf = (unsigned short*)alloc(T * 2);
    float*          oa        = (float*)alloc((long)MTOK * 384 * 4);
    unsigned short* sampo_bf  = (unsigned short*)alloc(T * 2);
    float*          ca        = (float*)alloc(T * 4);
    float*          t2        = (float*)alloc(T * 4);
    unsigned short* t2_bf     = (unsigned short*)alloc(T * 2);
    unsigned short* ffnh_bf   = (unsigned short*)alloc((long)MTOK * DFF_ * 2);
    float*          ffno      = (float*)alloc(T * 4);
    unsigned short* val       = (unsigned short*)alloc((long)MVAL * D_ * 2);
    // weight slices inside Wbf
    const unsigned short* wqkv  = Wbf + 0;        // 768 x 256
    const unsigned short* wo    = Wbf + 196608;
    const unsigned short* wsoaw = Wbf + 262144;   // 384 x 256
    const unsigned short* wvp   = Wbf + 360448;
    const unsigned short* wop   = Wbf + 425984;
    const unsigned short* wl1   = Wbf + 491520;
    const unsigned short* wl2   = Wbf + 753664;
    const float* bias_qkv = biasAll;
    const float* bias_oa  = biasAll + 768;

    const dim3 blk(256);
    const dim3 g_m(57, 2);   // 7200 rows, 256 cols (128x128 tiles)

    conv_weights<<<992, blk, 0, stream>>>(ipw, opw, sow, aww, vpw, outpw, l1w, l2w,
                                          ipb, sob, awb, Wbf, biasAll);
    // fused QKV projection: N=768; n<512 uses tgt+pos, n>=512 uses tgt
    gemm_f32a<true><<<dim3(57, 6), blk, 0, stream>>>(tgt, pos, wqkv, bias_qkv, QKV_bf,
                                                     MTOK, QKVS, D_, 512);
    // self-attention (fused QKV rows)
    attn_mfma<<<dim3(64, 15), blk, 0, stream>>>(QKV_bf, QKV_bf + 256, QKV_bf + 512, sa_bf);
    // out_proj
    gemm_mfma<false, false><<<g_m, blk, 0, stream>>>(sa_bf, wo, opb, saproj, MTOK, D_, D_);
    // t1 = LN2(tgt + saproj); qplus2_bf = bf16(t1 + pos) transposed (b,q)
    ln_kernel<<<1800, blk, 0, stream>>>(tgt, saproj, n2g, n2be, t1, pos, qplus2_bf, 0, 2);
    // value projection: identity row map, LDS C-epilogue
    gemm_f32d<<<dim3(1662, 2), blk, 0, stream>>>(mem, wvp, vpb, val, MVAL, D_, D_);
    // fused samp_off + attn_w (N=384, f32 out)
    gemm_mfma<false, false><<<dim3(57, 3), blk, 0, stream>>>(qplus2_bf, wsoaw, bias_oa, oa, MTOK, 384, D_);
    // deformable sampling (native-layout val)
    msdeform_kernel<<<7200, blk, 0, stream>>>(oa, refp, val, sampo_bf);
    // output projection
    gemm_mfma<false, false><<<g_m, blk, 0, stream>>>(sampo_bf, wop, outpb, ca, MTOK, D_, D_);
    // t2 = LN1(t1 + ca^T) + bf16 copy
    ln_kernel<<<1800, blk, 0, stream>>>(t1, ca, n1g, n1be, t2, nullptr, t2_bf, 1, 1);
    // FFN
    gemm_mfma<true, true><<<dim3(57, 8), blk, 0, stream>>>(t2_bf, wl1, l1b, ffnh_bf, MTOK, DFF_, D_);
    gemm_mfma<false, false><<<g_m, blk, 0, stream>>>(ffnh_bf, wl2, l2b, ffno, MTOK, D_, DFF_);
    // out = LN3(t2 + ffn)
    ln_kernel<<<1800, blk, 0, stream>>>(t2, ffno, n3g, n3be, (float*)d_out, nullptr, nullptr, 0, 0);
}